// Round 1
// baseline (1102.695 us; speedup 1.0000x reference)
//
#include <hip/hip_runtime.h>
#include <math.h>

typedef __bf16 bf16x8_t __attribute__((ext_vector_type(8)));
typedef unsigned short u16x8_t __attribute__((ext_vector_type(8)));
typedef float f32x4_t __attribute__((ext_vector_type(4)));
typedef float f32x2_t __attribute__((ext_vector_type(2)));

#define NB_TOTAL 200000
#define W1P_ELEMS 51200   // 10 ktiles * 10 jtiles * 64 lanes * 8
#define W2P_ELEMS 10240   // 5 ktiles * 4 jtiles * 64 lanes * 8

__device__ __forceinline__ unsigned short f2bf(float f) {
    unsigned int u = __builtin_bit_cast(unsigned int, f);
    u += 0x7fffu + ((u >> 16) & 1u);   // RNE
    return (unsigned short)(u >> 16);
}

__global__ void kzero(float* __restrict__ out, int n) {
    int i = blockIdx.x * 256 + threadIdx.x;
    if (i < n) out[i] = 0.0f;
}

// Repack W1 (320x160) and W2 (160x64) into MFMA B-fragment order, fp32 -> bf16.
// B-frag for mfma_f32_16x16x32_bf16: lane L holds B[k = (L>>4)*8 + e][n = L&15].
// Pack index: ((j*KT + kt)*64 + L)*8 + e  so a wave's loads are contiguous.
// Also: runtime-detect int64 batch (int32 view's last word == 0 => it's a high word).
__global__ void krepack(const float* __restrict__ W1, const float* __restrict__ W2,
                        const int* __restrict__ batch, int nb,
                        unsigned short* __restrict__ w1p, unsigned short* __restrict__ w2p,
                        int* __restrict__ flagp) {
    int tid = blockIdx.x * 256 + threadIdx.x;
    if (tid == 0) *flagp = (batch[nb - 1] == 0) ? 1 : 0;
    if (tid < W1P_ELEMS) {
        int e = tid & 7, L = (tid >> 3) & 63, q = tid >> 9;
        int kt = q % 10, j = q / 10;
        int krow = kt * 32 + (L >> 4) * 8 + e;
        int col  = j * 16 + (L & 15);
        w1p[tid] = f2bf(W1[krow * 160 + col]);
    } else if (tid < W1P_ELEMS + W2P_ELEMS) {
        int s = tid - W1P_ELEMS;
        int e = s & 7, L = (s >> 3) & 63, q = s >> 9;
        int kt = q % 5, j = q / 5;
        int krow = kt * 32 + (L >> 4) * 8 + e;
        int col  = j * 16 + (L & 15);
        w2p[s] = f2bf(W2[krow * 64 + col]);
    }
}

// Fused: features -> GEMM1+SiLU -> GEMM2 -> gate+symmetrize+rotate -> atomic pool.
// 1 block = 64 nodes, 4 waves, wave w owns node rows [16w, 16w+16).
// LDS (62 KB, 2 blocks/CU):
//   [0, 41984)      Fs bf16 [64][328]   (phases 1-2)  -> alph f32 [64][68] overlay (3-4)
//   [41984, 63488)  Hs bf16 [64][168]   (phases 2-3)  -> per-wave f4 staging overlay (1, 4)
__launch_bounds__(256, 2)
__global__ void kmega(const float* __restrict__ hA, const float* __restrict__ vA,
                      const float* __restrict__ tA, const float* __restrict__ lfA,
                      const int* __restrict__ batch,
                      const float* __restrict__ b1, const float* __restrict__ b2,
                      const unsigned short* __restrict__ w1p,
                      const unsigned short* __restrict__ w2p,
                      const int* __restrict__ flagp,
                      float* __restrict__ out)
{
    __shared__ __align__(16) unsigned char smem[63488];
    unsigned short* Fs = (unsigned short*)smem;              // [64][328]
    unsigned short* Hs = (unsigned short*)(smem + 41984);    // [64][168]
    float* alph = (float*)smem;                              // [64][68]

    const int tid  = threadIdx.x;
    const int w    = tid >> 6;
    const int L    = tid & 63;
    const int quad = L >> 4;
    const int c16  = L & 15;
    const long gbase = (long)blockIdx.x * 64;

    float* stage = (float*)(smem + 41984) + w * 768;  // [576 t floats][192 v floats]

    // ---------------- phase 1: features -> Fs (bf16) ----------------
    for (int i = 0; i < 16; ++i) {
        const int  n = w * 16 + i;
        const long g = gbase + n;
        const f32x4_t* tg4 = (const f32x4_t*)(tA + g * 576);
        const f32x4_t* vg4 = (const f32x4_t*)(vA + g * 192);
        f32x4_t* st4 = (f32x4_t*)stage;
        st4[L]      = tg4[L];
        st4[64 + L] = tg4[64 + L];
        if (L < 16) st4[128 + L] = tg4[128 + L];
        if (L < 48) st4[144 + L] = vg4[L];
        // h: cols [0,128), fully coalesced dwordx2
        const f32x2_t h2 = *(const f32x2_t*)(hA + g * 128 + 2 * L);
        Fs[n * 328 + 2 * L]     = f2bf(h2.x);
        Fs[n * 328 + 2 * L + 1] = f2bf(h2.y);
        // v_norm: cols [128,192)
        float vx = stage[576 + 3 * L], vy = stage[576 + 3 * L + 1], vz = stage[576 + 3 * L + 2];
        Fs[n * 328 + 128 + L] = f2bf(sqrtf(vx * vx + vy * vy + vz * vz));
        // t invariants interleaved trace/frob: cols [192,320)
        const float* tc = stage + 9 * L;
        float e0 = tc[0], e1 = tc[1], e2 = tc[2], e3 = tc[3], e4 = tc[4];
        float e5 = tc[5], e6 = tc[6], e7 = tc[7], e8 = tc[8];
        Fs[n * 328 + 192 + 2 * L] = f2bf(e0 + e4 + e8);
        Fs[n * 328 + 193 + 2 * L] = f2bf(sqrtf(e0*e0 + e1*e1 + e2*e2 + e3*e3 + e4*e4 +
                                               e5*e5 + e6*e6 + e7*e7 + e8*e8));
    }
    __syncthreads();

    // ---------------- phase 2: Hs = silu(F @ W1 + b1) ----------------
    // A-frag: lane L holds A[m = L&15][k = quad*8 + e] of this wave's 16-row tile.
    bf16x8_t afrag[10];
    {
        const unsigned short* frow = Fs + (w * 16 + c16) * 328;
        #pragma unroll
        for (int kt = 0; kt < 10; ++kt)
            afrag[kt] = __builtin_bit_cast(bf16x8_t, *(const u16x8_t*)(frow + kt * 32 + quad * 8));
    }
    {
        const u16x8_t* W1f = (const u16x8_t*)w1p;
        for (int j = 0; j < 10; ++j) {
            f32x4_t acc = {0.f, 0.f, 0.f, 0.f};
            #pragma unroll
            for (int kt = 0; kt < 10; ++kt) {
                bf16x8_t bfrag = __builtin_bit_cast(bf16x8_t, W1f[(j * 10 + kt) * 64 + L]);
                acc = __builtin_amdgcn_mfma_f32_16x16x32_bf16(afrag[kt], bfrag, acc, 0, 0, 0);
            }
            const float bias = b1[j * 16 + c16];
            #pragma unroll
            for (int r = 0; r < 4; ++r) {   // D: row m = quad*4 + r, col n = c16
                float x = acc[r] + bias;
                float sv = x / (1.0f + __expf(-x));   // SiLU
                Hs[(w * 16 + quad * 4 + r) * 168 + j * 16 + c16] = f2bf(sv);
            }
        }
    }
    __syncthreads();   // all waves done reading Fs before alph overlays it

    // ---------------- phase 3: alph = H @ W2 + b2 (fp32, in LDS) ----------------
    bf16x8_t a2[5];
    {
        const unsigned short* hrow = Hs + (w * 16 + c16) * 168;
        #pragma unroll
        for (int kt = 0; kt < 5; ++kt)
            a2[kt] = __builtin_bit_cast(bf16x8_t, *(const u16x8_t*)(hrow + kt * 32 + quad * 8));
    }
    {
        const u16x8_t* W2f = (const u16x8_t*)w2p;
        #pragma unroll
        for (int j = 0; j < 4; ++j) {
            f32x4_t acc = {0.f, 0.f, 0.f, 0.f};
            #pragma unroll
            for (int kt = 0; kt < 5; ++kt) {
                bf16x8_t bfrag = __builtin_bit_cast(bf16x8_t, W2f[(j * 5 + kt) * 64 + L]);
                acc = __builtin_amdgcn_mfma_f32_16x16x32_bf16(a2[kt], bfrag, acc, 0, 0, 0);
            }
            const float bias = b2[j * 16 + c16];
            #pragma unroll
            for (int r = 0; r < 4; ++r)
                alph[(w * 16 + quad * 4 + r) * 68 + j * 16 + c16] = acc[r] + bias;
        }
    }
    __syncthreads();   // all waves done reading Hs before staging overlays it

    // ---------------- phase 4: gate, symmetrize, rotate, pool ----------------
    const int is64 = *flagp;
    for (int i = 0; i < 16; ++i) {
        const int  n = w * 16 + i;
        const long g = gbase + n;
        const f32x4_t* tg4 = (const f32x4_t*)(tA + g * 576);
        f32x4_t* st4 = (f32x4_t*)stage;
        st4[L]      = tg4[L];
        st4[64 + L] = tg4[64 + L];
        if (L < 16) st4[128 + L] = tg4[128 + L];
        const float alpha = alph[n * 68 + L];      // own wave's rows: no barrier needed
        const float* tc = stage + 9 * L;
        float e0 = tc[0], e1 = tc[1], e2 = tc[2], e3 = tc[3], e4 = tc[4];
        float e5 = tc[5], e6 = tc[6], e7 = tc[7], e8 = tc[8];
        // symmetrized gated partials (6 unique entries of 0.5*(M+M^T))
        float p0 = alpha * e0;                    // S00
        float p1 = alpha * e4;                    // S11
        float p2 = alpha * e8;                    // S22
        float p3 = alpha * 0.5f * (e1 + e3);      // S01
        float p4 = alpha * 0.5f * (e2 + e6);      // S02
        float p5 = alpha * 0.5f * (e5 + e7);      // S12
        #pragma unroll
        for (int off = 32; off >= 1; off >>= 1) {
            p0 += __shfl_xor(p0, off, 64);
            p1 += __shfl_xor(p1, off, 64);
            p2 += __shfl_xor(p2, off, 64);
            p3 += __shfl_xor(p3, off, 64);
            p4 += __shfl_xor(p4, off, 64);
            p5 += __shfl_xor(p5, off, 64);
        }
        if (L == 0) {
            const float* Rp = lfA + g * 9;
            float R0=Rp[0],R1=Rp[1],R2=Rp[2],R3=Rp[3],R4=Rp[4],R5=Rp[5],R6=Rp[6],R7=Rp[7],R8=Rp[8];
            float S00=p0, S11=p1, S22=p2, S01=p3, S02=p4, S12=p5;
            // M = R * S (S symmetric)
            float M00 = R0*S00 + R1*S01 + R2*S02;
            float M01 = R0*S01 + R1*S11 + R2*S12;
            float M02 = R0*S02 + R1*S12 + R2*S22;
            float M10 = R3*S00 + R4*S01 + R5*S02;
            float M11 = R3*S01 + R4*S11 + R5*S12;
            float M12 = R3*S02 + R4*S12 + R5*S22;
            float M20 = R6*S00 + R7*S01 + R8*S02;
            float M21 = R6*S01 + R7*S11 + R8*S12;
            float M22 = R6*S02 + R7*S12 + R8*S22;
            int bg = is64 ? batch[2 * (int)g] : batch[(int)g];
            float* op = out + (long)bg * 9;
            // G = M * R^T
            atomicAdd(op + 0, M00*R0 + M01*R1 + M02*R2);
            atomicAdd(op + 1, M00*R3 + M01*R4 + M02*R5);
            atomicAdd(op + 2, M00*R6 + M01*R7 + M02*R8);
            atomicAdd(op + 3, M10*R0 + M11*R1 + M12*R2);
            atomicAdd(op + 4, M10*R3 + M11*R4 + M12*R5);
            atomicAdd(op + 5, M10*R6 + M11*R7 + M12*R8);
            atomicAdd(op + 6, M20*R0 + M21*R1 + M22*R2);
            atomicAdd(op + 7, M20*R3 + M21*R4 + M22*R5);
            atomicAdd(op + 8, M20*R6 + M21*R7 + M22*R8);
        }
    }
}

extern "C" void kernel_launch(void* const* d_in, const int* in_sizes, int n_in,
                              void* d_out, int out_size, void* d_ws, size_t ws_size,
                              hipStream_t stream)
{
    (void)n_in; (void)ws_size;
    const float* hA  = (const float*)d_in[0];
    const float* vA  = (const float*)d_in[1];
    const float* tA  = (const float*)d_in[2];
    const float* lfA = (const float*)d_in[3];
    const int*   bt  = (const int*)d_in[4];
    const float* W1  = (const float*)d_in[5];
    const float* b1  = (const float*)d_in[6];
    const float* W2  = (const float*)d_in[7];
    const float* b2  = (const float*)d_in[8];
    float* out = (float*)d_out;

    unsigned short* w1p = (unsigned short*)d_ws;                        // 102400 B
    unsigned short* w2p = (unsigned short*)((char*)d_ws + 102400);      // 20480 B
    int* flagp = (int*)((char*)d_ws + 122880);                          // 4 B

    kzero<<<(out_size + 255) / 256, 256, 0, stream>>>(out, out_size);
    krepack<<<240, 256, 0, stream>>>(W1, W2, bt, in_sizes[4], w1p, w2p, flagp);
    kmega<<<NB_TOTAL / 64, 256, 0, stream>>>(hA, vA, tA, lfA, bt, b1, b2, w1p, w2p, flagp, out);
}

// Round 2
// 855.165 us; speedup vs baseline: 1.2895x; 1.2895x over previous
//
#include <hip/hip_runtime.h>
#include <math.h>

typedef __bf16 bf16x8_t __attribute__((ext_vector_type(8)));
typedef unsigned short u16x8_t __attribute__((ext_vector_type(8)));
typedef float f32x4_t __attribute__((ext_vector_type(4)));
// unaligned-capable vectors (dword-aligned only): global_load_dwordxN needs only 4B align
typedef float f32x4u __attribute__((ext_vector_type(4), aligned(4)));
typedef float f32x2u __attribute__((ext_vector_type(2), aligned(4)));

#define NB_TOTAL 200000
#define W1P_ELEMS 51200   // 10 ktiles * 10 jtiles * 64 lanes * 8
#define W2P_ELEMS 10240   // 5 ktiles * 4 jtiles * 64 lanes * 8

__device__ __forceinline__ unsigned short f2bf(float f) {
    unsigned int u = __builtin_bit_cast(unsigned int, f);
    u += 0x7fffu + ((u >> 16) & 1u);   // RNE
    return (unsigned short)(u >> 16);
}

// Fs layout: [64 rows][320 cols] bf16, no padding (40960 B = 160KiB/4 exactly).
// Bank-conflict fix via XOR swizzle of 8-element (16B) chunks: chunk' = chunk ^ (row&7).
// A-frag b128 reads then hit each bank 2-way (free, m136) instead of 16-way.
__device__ __forceinline__ int fsoff(int n, int k) {
    return n * 320 + ((((k >> 3) ^ (n & 7)) << 3) | (k & 7));
}

__global__ void kzero(float* __restrict__ out, int n) {
    int i = blockIdx.x * 256 + threadIdx.x;
    if (i < n) out[i] = 0.0f;
}

// Repack W1 (320x160) and W2 (160x64) into MFMA B-fragment order, fp32 -> bf16.
// B-frag for mfma_f32_16x16x32_bf16: lane L holds B[k = (L>>4)*8 + e][n = L&15].
__global__ void krepack(const float* __restrict__ W1, const float* __restrict__ W2,
                        const int* __restrict__ batch, int nb,
                        unsigned short* __restrict__ w1p, unsigned short* __restrict__ w2p,
                        int* __restrict__ flagp) {
    int tid = blockIdx.x * 256 + threadIdx.x;
    if (tid == 0) *flagp = (batch[nb - 1] == 0) ? 1 : 0;   // int64 batch detection
    if (tid < W1P_ELEMS) {
        int e = tid & 7, L = (tid >> 3) & 63, q = tid >> 9;
        int kt = q % 10, j = q / 10;
        int krow = kt * 32 + (L >> 4) * 8 + e;
        int col  = j * 16 + (L & 15);
        w1p[tid] = f2bf(W1[krow * 160 + col]);
    } else if (tid < W1P_ELEMS + W2P_ELEMS) {
        int s = tid - W1P_ELEMS;
        int e = s & 7, L = (s >> 3) & 63, q = s >> 9;
        int kt = q % 5, j = q / 5;
        int krow = kt * 32 + (L >> 4) * 8 + e;
        int col  = j * 16 + (L & 15);
        w2p[s] = f2bf(W2[krow * 64 + col]);
    }
}

// Fused: features -> GEMM1+SiLU -> GEMM2 -> gate+symmetrize+rotate -> atomic pool.
// 1 block = 64 nodes, 4 waves; wave w owns node rows [16w, 16w+16).
// LDS = 40960 B -> 4 blocks/CU (16 waves/CU). Overlays (all A-frag reads are
// wave-own rows, so barriers only guard the overlays):
//   Fs bf16 [64][320] swizzled  --(barrier after afrag loads)--> Hs bf16 [64][168]
//   --(barrier after a2 loads)--> alph f32 [64][68]
__launch_bounds__(256, 4)
__global__ void kmega(const float* __restrict__ hA, const float* __restrict__ vA,
                      const float* __restrict__ tA, const float* __restrict__ lfA,
                      const int* __restrict__ batch,
                      const float* __restrict__ b1, const float* __restrict__ b2,
                      const unsigned short* __restrict__ w1p,
                      const unsigned short* __restrict__ w2p,
                      const int* __restrict__ flagp,
                      float* __restrict__ out)
{
    __shared__ __align__(16) unsigned char smem[40960];
    unsigned short* Fs = (unsigned short*)smem;   // [64][320] swizzled
    unsigned short* Hs = (unsigned short*)smem;   // [64][168] overlay
    float* alph = (float*)smem;                   // [64][68]  overlay

    const int tid  = threadIdx.x;
    const int w    = tid >> 6;
    const int L    = tid & 63;
    const int quad = L >> 4;
    const int c16  = L & 15;
    const long gbase = (long)blockIdx.x * 64;

    // ---------------- phase 1: features -> Fs (direct per-lane loads, high ILP) ----
    #pragma unroll 4
    for (int i = 0; i < 16; ++i) {
        const int  n = w * 16 + i;
        const long g = gbase + n;
        const float* tp = tA + g * 576 + 9 * L;       // lane's 9 contiguous floats
        const f32x4u t04 = *(const f32x4u*)tp;        // e0..e3
        const f32x4u t48 = *(const f32x4u*)(tp + 4);  // e4..e7
        const float  e8  = tp[8];
        const float* vp = vA + g * 192 + 3 * L;
        const f32x2u v01 = *(const f32x2u*)vp;
        const float  v2  = vp[2];
        const f32x2u h2 = *(const f32x2u*)(hA + g * 128 + 2 * L);
        // h: cols [0,128) as packed pairs
        unsigned hp = (unsigned)f2bf(h2.x) | ((unsigned)f2bf(h2.y) << 16);
        *(unsigned*)(Fs + fsoff(n, 2 * L)) = hp;
        // v_norm: col 128+L
        Fs[fsoff(n, 128 + L)] = f2bf(sqrtf(v01.x * v01.x + v01.y * v01.y + v2 * v2));
        // t invariants (trace, frob) interleaved: cols 192+2L, 193+2L
        float tr = t04.x + t48.x + e8;
        float fr = sqrtf(t04.x*t04.x + t04.y*t04.y + t04.z*t04.z + t04.w*t04.w +
                         t48.x*t48.x + t48.y*t48.y + t48.z*t48.z + t48.w*t48.w + e8*e8);
        unsigned tp2 = (unsigned)f2bf(tr) | ((unsigned)f2bf(fr) << 16);
        *(unsigned*)(Fs + fsoff(n, 192 + 2 * L)) = tp2;
    }

    // A-frags for GEMM1: lane L holds A[m = c16][k = quad*8 + e] of wave's 16-row tile.
    // Own-wave rows only -> no barrier before this.
    bf16x8_t afrag[10];
    {
        const int row = w * 16 + c16;
        const unsigned short* base = Fs + row * 320;
        const int sw = row & 7;
        #pragma unroll
        for (int kt = 0; kt < 10; ++kt) {
            const int c = kt * 4 + quad;
            afrag[kt] = __builtin_bit_cast(bf16x8_t, *(const u16x8_t*)(base + ((c ^ sw) << 3)));
        }
    }
    __syncthreads();   // Fs dead everywhere -> Hs overlay is safe

    // ---------------- phase 2: Hs = silu(F @ W1 + b1) ----------------
    {
        const u16x8_t* W1f = (const u16x8_t*)w1p;
        for (int j = 0; j < 10; ++j) {
            f32x4_t acc = {0.f, 0.f, 0.f, 0.f};
            #pragma unroll
            for (int kt = 0; kt < 10; ++kt) {
                bf16x8_t bfrag = __builtin_bit_cast(bf16x8_t, W1f[(j * 10 + kt) * 64 + L]);
                acc = __builtin_amdgcn_mfma_f32_16x16x32_bf16(afrag[kt], bfrag, acc, 0, 0, 0);
            }
            const float bias = b1[j * 16 + c16];
            #pragma unroll
            for (int r = 0; r < 4; ++r) {   // D: row m = quad*4 + r, col n = c16
                float x = acc[r] + bias;
                float sv = x / (1.0f + __expf(-x));   // SiLU
                Hs[(w * 16 + quad * 4 + r) * 168 + j * 16 + c16] = f2bf(sv);
            }
        }
    }

    // A-frags for GEMM2 (own-wave Hs rows -> no barrier)
    bf16x8_t a2[5];
    {
        const unsigned short* hrow = Hs + (w * 16 + c16) * 168;
        #pragma unroll
        for (int kt = 0; kt < 5; ++kt)
            a2[kt] = __builtin_bit_cast(bf16x8_t, *(const u16x8_t*)(hrow + kt * 32 + quad * 8));
    }
    __syncthreads();   // Hs dead everywhere -> alph overlay is safe

    // ---------------- phase 3: alph = H @ W2 + b2 (fp32, LDS) ----------------
    {
        const u16x8_t* W2f = (const u16x8_t*)w2p;
        #pragma unroll
        for (int j = 0; j < 4; ++j) {
            f32x4_t acc = {0.f, 0.f, 0.f, 0.f};
            #pragma unroll
            for (int kt = 0; kt < 5; ++kt) {
                bf16x8_t bfrag = __builtin_bit_cast(bf16x8_t, W2f[(j * 5 + kt) * 64 + L]);
                acc = __builtin_amdgcn_mfma_f32_16x16x32_bf16(a2[kt], bfrag, acc, 0, 0, 0);
            }
            const float bias = b2[j * 16 + c16];
            #pragma unroll
            for (int r = 0; r < 4; ++r)
                alph[(w * 16 + quad * 4 + r) * 68 + j * 16 + c16] = acc[r] + bias;
        }
    }

    // ---------------- phase 4: gate, symmetrize, rotate, pool ----------------
    const int is64 = *flagp;
    #pragma unroll 4
    for (int i = 0; i < 16; ++i) {
        const int  n = w * 16 + i;
        const long g = gbase + n;
        const float* tp = tA + g * 576 + 9 * L;
        const f32x4u t04 = *(const f32x4u*)tp;        // e0..e3
        const f32x4u t48 = *(const f32x4u*)(tp + 4);  // e4..e7
        const float  e8  = tp[8];
        const float alpha = alph[n * 68 + L];         // own-wave rows: no barrier
        // symmetrized gated partials (6 unique entries of 0.5*(M+M^T))
        float p0 = alpha * t04.x;                     // S00
        float p1 = alpha * t48.x;                     // S11
        float p2 = alpha * e8;                        // S22
        float p3 = alpha * 0.5f * (t04.y + t04.w);    // S01
        float p4 = alpha * 0.5f * (t04.z + t48.z);    // S02
        float p5 = alpha * 0.5f * (t48.y + t48.w);    // S12
        #pragma unroll
        for (int off = 32; off >= 1; off >>= 1) {
            p0 += __shfl_xor(p0, off, 64);
            p1 += __shfl_xor(p1, off, 64);
            p2 += __shfl_xor(p2, off, 64);
            p3 += __shfl_xor(p3, off, 64);
            p4 += __shfl_xor(p4, off, 64);
            p5 += __shfl_xor(p5, off, 64);
        }
        if (L < 9) {     // lane j writes output element (j/3, j%3)
            const float* Rp = lfA + g * 9;
            const int r = L / 3, c = L % 3;
            float Ra0 = Rp[3*r], Ra1 = Rp[3*r+1], Ra2 = Rp[3*r+2];
            float Rb0 = Rp[3*c], Rb1 = Rp[3*c+1], Rb2 = Rp[3*c+2];
            // u = S @ Rb (S symmetric), val = Ra . u
            float u0 = p0*Rb0 + p3*Rb1 + p4*Rb2;
            float u1 = p3*Rb0 + p1*Rb1 + p5*Rb2;
            float u2 = p4*Rb0 + p5*Rb1 + p2*Rb2;
            float val = Ra0*u0 + Ra1*u1 + Ra2*u2;
            const int gi = (int)g;
            const int bg = is64 ? batch[2 * gi] : batch[gi];
            atomicAdd(out + (long)bg * 9 + L, val);
        }
    }
}

extern "C" void kernel_launch(void* const* d_in, const int* in_sizes, int n_in,
                              void* d_out, int out_size, void* d_ws, size_t ws_size,
                              hipStream_t stream)
{
    (void)n_in; (void)ws_size;
    const float* hA  = (const float*)d_in[0];
    const float* vA  = (const float*)d_in[1];
    const float* tA  = (const float*)d_in[2];
    const float* lfA = (const float*)d_in[3];
    const int*   bt  = (const int*)d_in[4];
    const float* W1  = (const float*)d_in[5];
    const float* b1  = (const float*)d_in[6];
    const float* W2  = (const float*)d_in[7];
    const float* b2  = (const float*)d_in[8];
    float* out = (float*)d_out;

    unsigned short* w1p = (unsigned short*)d_ws;                        // 102400 B
    unsigned short* w2p = (unsigned short*)((char*)d_ws + 102400);      // 20480 B
    int* flagp = (int*)((char*)d_ws + 122880);                          // 4 B

    kzero<<<(out_size + 255) / 256, 256, 0, stream>>>(out, out_size);
    krepack<<<240, 256, 0, stream>>>(W1, W2, bt, in_sizes[4], w1p, w2p, flagp);
    kmega<<<NB_TOTAL / 64, 256, 0, stream>>>(hA, vA, tA, lfA, bt, b1, b2, w1p, w2p, flagp, out);
}